// Round 3
// baseline (507.548 us; speedup 1.0000x reference)
//
#include <hip/hip_runtime.h>
#include <hip/hip_bf16.h>

typedef unsigned short u16;
typedef __bf16 bf16x8 __attribute__((ext_vector_type(8)));
typedef float f32x4 __attribute__((ext_vector_type(4)));

#define B_   2
#define S_   2048
#define HID_ 2048
#define H_   16
#define KV_  4
#define D_   128

template <int V> struct ic { static constexpr int value = V; };

__device__ __forceinline__ u16 f2b(float f) {
  unsigned u = __float_as_uint(f);
  return (u16)((u + 0x7fffu + ((u >> 16) & 1u)) >> 16);  // RNE
}
__device__ __forceinline__ float b2f(u16 h) {
  return __uint_as_float(((unsigned)h) << 16);
}
__device__ __forceinline__ unsigned pk2(float a, float b) {
  __hip_bfloat162 h = __float22bfloat162_rn(make_float2(a, b));
  unsigned u;
  __builtin_memcpy(&u, &h, 4);
  return u;  // a low 16, b high 16
}
__device__ __forceinline__ void cstore(float* p, float v) { *p = v; }
__device__ __forceinline__ void cstore(u16* p, float v)   { *p = f2b(v); }

// async global->LDS, 16B per lane; LDS dest = wave-uniform base + lane*16
__device__ __forceinline__ void gl_lds16(const u16* g, u16* l) {
  __builtin_amdgcn_global_load_lds(
      (const __attribute__((address_space(1))) unsigned int*)g,
      (__attribute__((address_space(3))) unsigned int*)l, 16, 0, 0);
}

// ---------------------------------------------------------------- cast x -> bf16
__global__ __launch_bounds__(256)
void cast_f2b_kernel(const float* __restrict__ in, u16* __restrict__ out, int n) {
  int i = (blockIdx.x * 256 + threadIdx.x) * 4;
  if (i + 3 < n) {
    float4 v = *(const float4*)(in + i);
    uint2 r = make_uint2(pk2(v.x, v.y), pk2(v.z, v.w));
    *(uint2*)(out + i) = r;
  }
}

// ------------------------------------------- W (R x C) fp32 -> Wt (C x R) bf16
__global__ __launch_bounds__(256)
void transpose_w_kernel(const float* __restrict__ in, u16* __restrict__ out,
                        int R, int Cc) {
  __shared__ u16 t[32][33];
  const int tx = threadIdx.x, ty = threadIdx.y;
  const int c0 = blockIdx.x * 32, r0 = blockIdx.y * 32;
#pragma unroll
  for (int i = 0; i < 4; i++)
    t[ty + i * 8][tx] = f2b(in[(size_t)(r0 + ty + i * 8) * Cc + c0 + tx]);
  __syncthreads();
#pragma unroll
  for (int i = 0; i < 4; i++)
    out[(size_t)(c0 + ty + i * 8) * R + r0 + tx] = t[tx][ty + i * 8];
}

// ------------------- v slice of kvraw (tok, TS) -> Vt (B,KV,D,S) bf16
__global__ __launch_bounds__(256)
void transpose_v_kernel(const u16* __restrict__ in, u16* __restrict__ out,
                        int tokstride) {
  __shared__ u16 t[32][33];
  const int tx = threadIdx.x, ty = threadIdx.y;
  const int s0 = blockIdx.x * 32, d0 = blockIdx.y * 32;
  const int z = blockIdx.z, b = z >> 2, kv = z & 3;
#pragma unroll
  for (int i = 0; i < 4; i++)
    t[ty + i * 8][tx] =
        in[(size_t)(b * S_ + s0 + ty + i * 8) * tokstride + kv * D_ + d0 + tx];
  __syncthreads();
#pragma unroll
  for (int i = 0; i < 4; i++)
    out[((size_t)(b * KV_ + kv) * D_ + d0 + ty + i * 8) * S_ + s0 + tx] =
        t[tx][ty + i * 8];
}

// --------------------------------- NT GEMM: A (M,K) bf16, Bt (N,K) bf16, C (M,N)
// m97 structure: 128x128 tile, BK=32, global_load_lds width=16, unpadded LDS.
template <typename CT>
__global__ __launch_bounds__(256)
void gemm_nt(const u16* __restrict__ A, const u16* __restrict__ Bt,
             CT* __restrict__ C, int Md, int Nd, int Kd) {
  __shared__ u16 As[128 * 32];
  __shared__ u16 Bs[128 * 32];
  const int tid = threadIdx.x;
  const int lane = tid & 63;
  const int wave = tid >> 6;
  const int wm = wave >> 1, wn = wave & 1;
  const int li = lane & 15, quad = lane >> 4;
  const int m0 = blockIdx.y * 128;
  const int n0 = blockIdx.x * 128;

  f32x4 acc[4][4];
#pragma unroll
  for (int i = 0; i < 4; i++)
#pragma unroll
    for (int j = 0; j < 4; j++) acc[i][j] = (f32x4){0.f, 0.f, 0.f, 0.f};

  const int srow = wave * 32 + (lane >> 2);
  const int scol = (lane & 3) * 8;
  const u16* Ag0 = A + (size_t)(m0 + srow) * Kd + scol;
  const u16* Ag1 = Ag0 + (size_t)16 * Kd;
  const u16* Bg0 = Bt + (size_t)(n0 + srow) * Kd + scol;
  const u16* Bg1 = Bg0 + (size_t)16 * Kd;
  u16* Al0 = &As[(wave * 32) * 32];
  u16* Al1 = &As[(wave * 32 + 16) * 32];
  u16* Bl0 = &Bs[(wave * 32) * 32];
  u16* Bl1 = &Bs[(wave * 32 + 16) * 32];

  for (int k0 = 0; k0 < Kd; k0 += 32) {
    __syncthreads();
    gl_lds16(Ag0 + k0, Al0);
    gl_lds16(Ag1 + k0, Al1);
    gl_lds16(Bg0 + k0, Bl0);
    gl_lds16(Bg1 + k0, Bl1);
    __syncthreads();
    bf16x8 af[4], bfr[4];
#pragma unroll
    for (int mt = 0; mt < 4; mt++)
      af[mt] = *(const bf16x8*)&As[(wm * 64 + mt * 16 + li) * 32 + quad * 8];
#pragma unroll
    for (int nt = 0; nt < 4; nt++)
      bfr[nt] = *(const bf16x8*)&Bs[(wn * 64 + nt * 16 + li) * 32 + quad * 8];
#pragma unroll
    for (int mt = 0; mt < 4; mt++)
#pragma unroll
      for (int nt = 0; nt < 4; nt++)
        acc[mt][nt] = __builtin_amdgcn_mfma_f32_16x16x32_bf16(
            af[mt], bfr[nt], acc[mt][nt], 0, 0, 0);
  }
#pragma unroll
  for (int mt = 0; mt < 4; mt++) {
    const int row = m0 + wm * 64 + mt * 16 + quad * 4;
#pragma unroll
    for (int nt = 0; nt < 4; nt++) {
      const int col = n0 + wn * 64 + nt * 16 + li;
#pragma unroll
      for (int r = 0; r < 4; r++)
        cstore(&C[(size_t)(row + r) * Nd + col], acc[mt][nt][r]);
    }
  }
}

// ------------------------ fused RMSNorm (w+1) + RoPE (+ optional score scale)
__global__ __launch_bounds__(256)
void rmsrope_kernel(const u16* __restrict__ in, const float* __restrict__ w,
                    u16* __restrict__ out, int n_heads, int tok_stride,
                    int head_stride, float scale) {
  const int warp = (blockIdx.x << 2) + (threadIdx.x >> 6);
  const int lane = threadIdx.x & 63;
  const int h = warp % n_heads;
  const int tok = warp / n_heads;
  const int s = tok & (S_ - 1);
  const int b = tok >> 11;
  const u16* src = in + (size_t)tok * tok_stride + (size_t)h * head_stride;
  float x1 = b2f(src[lane]);
  float x2 = b2f(src[lane + 64]);
  float ss = x1 * x1 + x2 * x2;
#pragma unroll
  for (int off = 1; off < 64; off <<= 1) ss += __shfl_xor(ss, off);
  const float inv = rsqrtf(ss * (1.0f / 128.0f) + 1e-6f) * scale;
  x1 *= inv * (w[lane] + 1.0f);
  x2 *= inv * (w[lane + 64] + 1.0f);
  const float invf = exp2f((float)lane * (-19.931568569324174f / 64.0f));
  const float ang = (float)s * invf;
  float sn, c;
  sincosf(ang, &sn, &c);
  const size_t ob = (((size_t)b * n_heads + h) * S_ + s) * D_;
  out[ob + lane]      = f2b(x1 * c - x2 * sn);
  out[ob + lane + 64] = f2b(x2 * c + x1 * sn);
}

// --------------------------- flash attention: 2-wave split-K per 32-row strip.
// Grid is 1D; blockIdx.x & 7 selects the (b,kv) group so that round-robin
// workgroup->XCD dispatch pins each group's K/V (1MB) + Q (2MB) into ONE
// XCD's 4MB L2 (blocks id%8==g all land on XCD g). Heavy strips first within
// each group. All oacc[] indices compile-time (rule #20) via templated
// epilogue lambdas.
__global__ __launch_bounds__(128, 2)
void attn_kernel(const u16* __restrict__ Q, const u16* __restrict__ Kr,
                 const u16* __restrict__ Vt, const u16* __restrict__ qraw,
                 u16* __restrict__ Ag) {
  // per-wave scratch: P staging (loop phase, 2560B) unioned with the f32
  // O-exchange buffer [32][68] (epilogue phase, 8704B). 17.9KB total.
  __shared__ __align__(16) float Wscr[2][2176];
  __shared__ float Mdump[2][32], Ldump[2][32];

  const int tid = threadIdx.x;
  const int lane = tid & 63;
  const int wv = tid >> 6;  // K-split half (0 = low tiles, 1 = high tiles)
  const int li = lane & 15, quad = lane >> 4;

  // XCD-pinned decode: id%8 = (b,kv) group -> one XCD's L2 holds its K/V/Q.
  const int id = blockIdx.x;
  const int grp = id & 7;
  const int b = grp >> 2, kv = grp & 3;
  const int rest = id >> 3;          // 0..255 within group
  const int hh = rest & 3;           // head within kv group
  const int t = 63 - (rest >> 2);    // heavy strips first
  const int h = (kv << 2) | hh;
  const int bh = (b << 4) | h;
  const int rs = t * 32;  // strip q-row base

  const u16* Qb = Q + ((size_t)bh * S_ + rs) * D_;
  const u16* Kb = Kr + ((size_t)b * KV_ + kv) * S_ * D_;
  const u16* Vb = Vt + ((size_t)b * KV_ + kv) * D_ * S_;
  u16* Pscr = (u16*)&Wscr[wv][0];

  bf16x8 qf[2][4];  // B-operand of Q^T
#pragma unroll
  for (int n = 0; n < 2; n++)
#pragma unroll
    for (int dc = 0; dc < 4; dc++)
      qf[n][dc] =
          *(const bf16x8*)(Qb + (size_t)(n * 16 + li) * D_ + dc * 32 + quad * 8);

  float m_s[2] = {-1e30f, -1e30f}, l_s[2] = {0.f, 0.f};
  f32x4 oacc[2][8];
#pragma unroll
  for (int n = 0; n < 2; n++)
#pragma unroll
    for (int mt = 0; mt < 8; mt++) oacc[n][mt] = (f32x4){0.f, 0.f, 0.f, 0.f};

  // K-range split: wave0 [0,h0), wave1 [h0, t]; wave1 owns the diagonal.
  const int h0 = (t + 2) >> 1;
  const int klo = wv ? h0 : 0;
  const int khi = wv ? (t + 1) : h0;

  bf16x8 ka[2][4], kb2[2][4];  // K double buffer

  auto loadK = [&](bf16x8 (&kf)[2][4], int j0) {
#pragma unroll
    for (int mt = 0; mt < 2; mt++)
#pragma unroll
      for (int dc = 0; dc < 4; dc++)
        kf[mt][dc] = *(const bf16x8*)(Kb + (size_t)(j0 + mt * 16 + li) * D_ +
                                      dc * 32 + quad * 8);
  };

  auto step = [&](bf16x8 (&kf)[2][4], bf16x8 (&kn)[2][4], int jt) {
    const int j0 = jt * 32;
    // V loads for this tile (consumed after softmax) — issue first
    bf16x8 vf[8];
#pragma unroll
    for (int mt = 0; mt < 8; mt++)
      vf[mt] = *(const bf16x8*)(Vb + (size_t)(mt * 16 + li) * S_ + j0 + quad * 8);
    // prefetch next tile's K into the other buffer (consumed next iteration)
    if (jt + 1 < khi) loadK(kn, j0 + 32);

    // S^T = K·Q^T on the resident buffer (no vm wait on in-flight loads)
    f32x4 sacc[2][2];
#pragma unroll
    for (int n = 0; n < 2; n++)
#pragma unroll
      for (int mt = 0; mt < 2; mt++) sacc[n][mt] = (f32x4){0.f, 0.f, 0.f, 0.f};
#pragma unroll
    for (int dc = 0; dc < 4; dc++)
#pragma unroll
      for (int mt = 0; mt < 2; mt++) {
        sacc[0][mt] = __builtin_amdgcn_mfma_f32_16x16x32_bf16(
            kf[mt][dc], qf[0][dc], sacc[0][mt], 0, 0, 0);
        sacc[1][mt] = __builtin_amdgcn_mfma_f32_16x16x32_bf16(
            kf[mt][dc], qf[1][dc], sacc[1][mt], 0, 0, 0);
      }

    if (jt == t) {  // diagonal tile causal mask
#pragma unroll
      for (int n = 0; n < 2; n++)
#pragma unroll
        for (int mt = 0; mt < 2; mt++)
#pragma unroll
          for (int r = 0; r < 4; r++)
            if (mt * 16 + quad * 4 + r > n * 16 + li) sacc[n][mt][r] = -1e30f;
    }
    // online softmax per n-tile (stats across quads: 2 shuffles)
    float alpha2[2];
#pragma unroll
    for (int n = 0; n < 2; n++) {
      float mx = -1e30f;
#pragma unroll
      for (int mt = 0; mt < 2; mt++)
#pragma unroll
        for (int r = 0; r < 4; r++) mx = fmaxf(mx, sacc[n][mt][r]);
      mx = fmaxf(mx, __shfl_xor(mx, 16));
      mx = fmaxf(mx, __shfl_xor(mx, 32));
      const float mn = fmaxf(m_s[n], mx);
      alpha2[n] = __expf(m_s[n] - mn);
      m_s[n] = mn;
      float rsum = 0.f;
#pragma unroll
      for (int mt = 0; mt < 2; mt++)
#pragma unroll
        for (int r = 0; r < 4; r++) {
          float p = __expf(sacc[n][mt][r] - mn);
          sacc[n][mt][r] = p;
          rsum += p;
        }
      rsum += __shfl_xor(rsum, 16);
      rsum += __shfl_xor(rsum, 32);
      l_s[n] = l_s[n] * alpha2[n] + rsum;
      // P (C-layout) -> LDS rows [q][k]
#pragma unroll
      for (int mt = 0; mt < 2; mt++) {
        uint2 w2;
        w2.x = pk2(sacc[n][mt][0], sacc[n][mt][1]);
        w2.y = pk2(sacc[n][mt][2], sacc[n][mt][3]);
        *(uint2*)&Pscr[(n * 16 + li) * 40 + mt * 16 + quad * 4] = w2;
      }
    }
    // rescale O while the LDS writes land (skip when no max moved)
    if (__any((alpha2[0] < 1.f) || (alpha2[1] < 1.f))) {
#pragma unroll
      for (int n = 0; n < 2; n++)
#pragma unroll
        for (int mt = 0; mt < 8; mt++) {
          oacc[n][mt][0] *= alpha2[n];
          oacc[n][mt][1] *= alpha2[n];
          oacc[n][mt][2] *= alpha2[n];
          oacc[n][mt][3] *= alpha2[n];
        }
    }
    asm volatile("s_waitcnt lgkmcnt(0)" ::: "memory");  // wave-private scratch
    bf16x8 pf[2];
    pf[0] = *(const bf16x8*)&Pscr[li * 40 + quad * 8];
    pf[1] = *(const bf16x8*)&Pscr[(16 + li) * 40 + quad * 8];
#pragma unroll
    for (int mt = 0; mt < 8; mt++) {
      oacc[0][mt] = __builtin_amdgcn_mfma_f32_16x16x32_bf16(vf[mt], pf[0],
                                                            oacc[0][mt], 0, 0, 0);
      oacc[1][mt] = __builtin_amdgcn_mfma_f32_16x16x32_bf16(vf[mt], pf[1],
                                                            oacc[1][mt], 0, 0, 0);
    }
  };

  if (klo < khi) {
    loadK(ka, klo * 32);
    for (int jt = klo; jt < khi; jt += 2) {
      step(ka, kb2, jt);
      if (jt + 1 < khi) step(kb2, ka, jt + 1);
    }
  }

  // ---- cross-wave flash merge. Phase 1: each wave dumps the COMPLEMENTARY
  // output half (+ its m,l) to its own LDS region. All oacc indices are
  // compile-time via the WV template constant.
  float* myscr = &Wscr[wv][0];
  auto dumpO = [&](auto wvc) {
    constexpr int WV = decltype(wvc)::value;
#pragma unroll
    for (int n = 0; n < 2; n++) {
      const int row = n * 16 + li;
#pragma unroll
      for (int mtl = 0; mtl < 4; mtl++)
        *(f32x4*)&myscr[row * 68 + mtl * 16 + quad * 4] =
            oacc[n][(1 - WV) * 4 + mtl];
      if (quad == 0) {
        Mdump[WV][row] = m_s[n];
        Ldump[WV][row] = l_s[n];
      }
    }
  };
  if (wv == 0) dumpO(ic<0>{}); else dumpO(ic<1>{});
  __syncthreads();
  // Phase 2: each wave finalizes (merge + gate + store) its OWN half.
  auto finO = [&](auto wvc) {
    constexpr int WV = decltype(wvc)::value;
    const float* oscr = &Wscr[1 - WV][0];
#pragma unroll
    for (int n = 0; n < 2; n++) {
      const int row = n * 16 + li;
      const float mo = Mdump[1 - WV][row];
      const float lo2 = Ldump[1 - WV][row];
      const float mm = fmaxf(m_s[n], mo);
      const float as = __expf(m_s[n] - mm), ao = __expf(mo - mm);
      const float linv = 1.f / (l_s[n] * as + lo2 * ao);
      const size_t tok = (size_t)b * S_ + rs + row;
      const u16* gp = qraw + tok * 4096 + h * 256 + 128;
      u16* op = Ag + tok * 2048 + h * 128;
#pragma unroll
      for (int mtl = 0; mtl < 4; mtl++) {
        const int dbase = (WV * 4 + mtl) * 16 + quad * 4;
        f32x4 oo = *(const f32x4*)&oscr[row * 68 + mtl * 16 + quad * 4];
        uint2 gv = *(const uint2*)(gp + dbase);
        float g0 = b2f((u16)(gv.x & 0xffff)), g1 = b2f((u16)(gv.x >> 16));
        float g2 = b2f((u16)(gv.y & 0xffff)), g3 = b2f((u16)(gv.y >> 16));
        float o0 = (oacc[n][WV * 4 + mtl][0] * as + oo[0] * ao) * linv /
                   (1.f + __expf(-g0));
        float o1 = (oacc[n][WV * 4 + mtl][1] * as + oo[1] * ao) * linv /
                   (1.f + __expf(-g1));
        float o2 = (oacc[n][WV * 4 + mtl][2] * as + oo[2] * ao) * linv /
                   (1.f + __expf(-g2));
        float o3 = (oacc[n][WV * 4 + mtl][3] * as + oo[3] * ao) * linv /
                   (1.f + __expf(-g3));
        *(uint2*)(op + dbase) = make_uint2(pk2(o0, o1), pk2(o2, o3));
      }
    }
  };
  if (wv == 0) finO(ic<0>{}); else finO(ic<1>{});
}

extern "C" void kernel_launch(void* const* d_in, const int* in_sizes, int n_in,
                              void* d_out, int out_size, void* d_ws,
                              size_t ws_size, hipStream_t stream) {
  const float* x  = (const float*)d_in[0];
  const float* Wq = (const float*)d_in[1];
  const float* Wk = (const float*)d_in[2];
  const float* Wv = (const float*)d_in[3];
  const float* Wo = (const float*)d_in[4];
  const float* qn = (const float*)d_in[5];
  const float* kn = (const float*)d_in[6];
  float* out = (float*)d_out;
  char* ws = (char*)d_ws;

  u16* xb    = (u16*)(ws + 0);          // 16.8 MB  x bf16 (4096x2048)
  u16* Wqt   = (u16*)(ws + 16777216);   // 16.8 MB  Wq^T (4096x2048)
  u16* Wkvt  = (u16*)(ws + 33554432);   //  4.2 MB  [Wk^T; Wv^T] (1024x2048)
  u16* Wot   = (u16*)(ws + 37748736);   //  8.4 MB  Wo^T (2048x2048)
  u16* qraw  = (u16*)(ws + 46137344);   // 33.6 MB  q_raw (4096x4096)
  u16* kvraw = (u16*)(ws + 79691776);   //  8.4 MB  [k|v] (4096x1024)
  u16* Vtb   = (u16*)(ws + 88080384);   //  4.2 MB  V^T (B,KV,D,S)
  u16* Kr    = (u16*)(ws + 92274688);   //  4.2 MB  K roped (B,KV,S,D)
  u16* Ag    = (u16*)(ws + 96468992);   // 16.8 MB  gated attn (4096x2048)
  u16* Qr = xb;  // (B,H,S,D) roped+scaled Q (aliases xb, dead after GEMMs)

  cast_f2b_kernel<<<8192, 256, 0, stream>>>(x, xb, 4096 * 2048);
  transpose_w_kernel<<<dim3(128, 64), dim3(32, 8), 0, stream>>>(Wq, Wqt, 2048, 4096);
  transpose_w_kernel<<<dim3(16, 64), dim3(32, 8), 0, stream>>>(Wk, Wkvt, 2048, 512);
  transpose_w_kernel<<<dim3(16, 64), dim3(32, 8), 0, stream>>>(Wv, Wkvt + 512 * 2048,
                                                               2048, 512);
  transpose_w_kernel<<<dim3(64, 64), dim3(32, 8), 0, stream>>>(Wo, Wot, 2048, 2048);

  gemm_nt<u16><<<dim3(32, 32), 256, 0, stream>>>(xb, Wqt, qraw, 4096, 4096, 2048);
  gemm_nt<u16><<<dim3(8, 32), 256, 0, stream>>>(xb, Wkvt, kvraw, 4096, 1024, 2048);

  // softmax scale folded into Q (Q only feeds scores; gate comes from qraw)
  rmsrope_kernel<<<16384, 256, 0, stream>>>(qraw, qn, Qr, 16, 4096, 256,
                                            0.08838834764831845f);
  rmsrope_kernel<<<4096, 256, 0, stream>>>(kvraw, kn, Kr, 4, 1024, 128, 1.0f);
  transpose_v_kernel<<<dim3(64, 4, 8), dim3(32, 8), 0, stream>>>(kvraw + 512, Vtb,
                                                                 1024);

  attn_kernel<<<2048, 128, 0, stream>>>(Qr, Kr, Vtb, qraw, Ag);
  gemm_nt<float><<<dim3(16, 32), 256, 0, stream>>>(Ag, Wot, out, 4096, 2048, 2048);
}

// Round 4
// 498.495 us; speedup vs baseline: 1.0182x; 1.0182x over previous
//
#include <hip/hip_runtime.h>
#include <hip/hip_bf16.h>

typedef unsigned short u16;
typedef __bf16 bf16x8 __attribute__((ext_vector_type(8)));
typedef float f32x4 __attribute__((ext_vector_type(4)));
typedef float f32x16 __attribute__((ext_vector_type(16)));

#define B_   2
#define S_   2048
#define HID_ 2048
#define H_   16
#define KV_  4
#define D_   128

template <int V> struct ic { static constexpr int value = V; };

__device__ __forceinline__ u16 f2b(float f) {
  unsigned u = __float_as_uint(f);
  return (u16)((u + 0x7fffu + ((u >> 16) & 1u)) >> 16);  // RNE
}
__device__ __forceinline__ float b2f(u16 h) {
  return __uint_as_float(((unsigned)h) << 16);
}
__device__ __forceinline__ unsigned pk2(float a, float b) {
  __hip_bfloat162 h = __float22bfloat162_rn(make_float2(a, b));
  unsigned u;
  __builtin_memcpy(&u, &h, 4);
  return u;  // a low 16, b high 16
}
__device__ __forceinline__ void cstore(float* p, float v) { *p = v; }
__device__ __forceinline__ void cstore(u16* p, float v)   { *p = f2b(v); }

// async global->LDS, 16B per lane; LDS dest = wave-uniform base + lane*16
__device__ __forceinline__ void gl_lds16(const u16* g, u16* l) {
  __builtin_amdgcn_global_load_lds(
      (const __attribute__((address_space(1))) unsigned int*)g,
      (__attribute__((address_space(3))) unsigned int*)l, 16, 0, 0);
}

// ---------------------------------------------------------------- cast x -> bf16
__global__ __launch_bounds__(256)
void cast_f2b_kernel(const float* __restrict__ in, u16* __restrict__ out, int n) {
  int i = (blockIdx.x * 256 + threadIdx.x) * 4;
  if (i + 3 < n) {
    float4 v = *(const float4*)(in + i);
    uint2 r = make_uint2(pk2(v.x, v.y), pk2(v.z, v.w));
    *(uint2*)(out + i) = r;
  }
}

// ------------------------------------------- W (R x C) fp32 -> Wt (C x R) bf16
__global__ __launch_bounds__(256)
void transpose_w_kernel(const float* __restrict__ in, u16* __restrict__ out,
                        int R, int Cc) {
  __shared__ u16 t[32][33];
  const int tx = threadIdx.x, ty = threadIdx.y;
  const int c0 = blockIdx.x * 32, r0 = blockIdx.y * 32;
#pragma unroll
  for (int i = 0; i < 4; i++)
    t[ty + i * 8][tx] = f2b(in[(size_t)(r0 + ty + i * 8) * Cc + c0 + tx]);
  __syncthreads();
#pragma unroll
  for (int i = 0; i < 4; i++)
    out[(size_t)(c0 + ty + i * 8) * R + r0 + tx] = t[tx][ty + i * 8];
}

// ------------------- v slice of kvraw (tok, TS) -> Vt (B,KV,D,S) bf16
__global__ __launch_bounds__(256)
void transpose_v_kernel(const u16* __restrict__ in, u16* __restrict__ out,
                        int tokstride) {
  __shared__ u16 t[32][33];
  const int tx = threadIdx.x, ty = threadIdx.y;
  const int s0 = blockIdx.x * 32, d0 = blockIdx.y * 32;
  const int z = blockIdx.z, b = z >> 2, kv = z & 3;
#pragma unroll
  for (int i = 0; i < 4; i++)
    t[ty + i * 8][tx] =
        in[(size_t)(b * S_ + s0 + ty + i * 8) * tokstride + kv * D_ + d0 + tx];
  __syncthreads();
#pragma unroll
  for (int i = 0; i < 4; i++)
    out[((size_t)(b * KV_ + kv) * D_ + d0 + ty + i * 8) * S_ + s0 + tx] =
        t[tx][ty + i * 8];
}

// --------------------------------- NT GEMM: A (M,K) bf16, Bt (N,K) bf16, C (M,N)
// m97 structure: 128x128 tile, BK=32, global_load_lds width=16, unpadded LDS.
template <typename CT>
__global__ __launch_bounds__(256)
void gemm_nt(const u16* __restrict__ A, const u16* __restrict__ Bt,
             CT* __restrict__ C, int Md, int Nd, int Kd) {
  __shared__ u16 As[128 * 32];
  __shared__ u16 Bs[128 * 32];
  const int tid = threadIdx.x;
  const int lane = tid & 63;
  const int wave = tid >> 6;
  const int wm = wave >> 1, wn = wave & 1;
  const int li = lane & 15, quad = lane >> 4;
  const int m0 = blockIdx.y * 128;
  const int n0 = blockIdx.x * 128;

  f32x4 acc[4][4];
#pragma unroll
  for (int i = 0; i < 4; i++)
#pragma unroll
    for (int j = 0; j < 4; j++) acc[i][j] = (f32x4){0.f, 0.f, 0.f, 0.f};

  const int srow = wave * 32 + (lane >> 2);
  const int scol = (lane & 3) * 8;
  const u16* Ag0 = A + (size_t)(m0 + srow) * Kd + scol;
  const u16* Ag1 = Ag0 + (size_t)16 * Kd;
  const u16* Bg0 = Bt + (size_t)(n0 + srow) * Kd + scol;
  const u16* Bg1 = Bg0 + (size_t)16 * Kd;
  u16* Al0 = &As[(wave * 32) * 32];
  u16* Al1 = &As[(wave * 32 + 16) * 32];
  u16* Bl0 = &Bs[(wave * 32) * 32];
  u16* Bl1 = &Bs[(wave * 32 + 16) * 32];

  for (int k0 = 0; k0 < Kd; k0 += 32) {
    __syncthreads();
    gl_lds16(Ag0 + k0, Al0);
    gl_lds16(Ag1 + k0, Al1);
    gl_lds16(Bg0 + k0, Bl0);
    gl_lds16(Bg1 + k0, Bl1);
    __syncthreads();
    bf16x8 af[4], bfr[4];
#pragma unroll
    for (int mt = 0; mt < 4; mt++)
      af[mt] = *(const bf16x8*)&As[(wm * 64 + mt * 16 + li) * 32 + quad * 8];
#pragma unroll
    for (int nt = 0; nt < 4; nt++)
      bfr[nt] = *(const bf16x8*)&Bs[(wn * 64 + nt * 16 + li) * 32 + quad * 8];
#pragma unroll
    for (int mt = 0; mt < 4; mt++)
#pragma unroll
      for (int nt = 0; nt < 4; nt++)
        acc[mt][nt] = __builtin_amdgcn_mfma_f32_16x16x32_bf16(
            af[mt], bfr[nt], acc[mt][nt], 0, 0, 0);
  }
#pragma unroll
  for (int mt = 0; mt < 4; mt++) {
    const int row = m0 + wm * 64 + mt * 16 + quad * 4;
#pragma unroll
    for (int nt = 0; nt < 4; nt++) {
      const int col = n0 + wn * 64 + nt * 16 + li;
#pragma unroll
      for (int r = 0; r < 4; r++)
        cstore(&C[(size_t)(row + r) * Nd + col], acc[mt][nt][r]);
    }
  }
}

// ------------------------ fused RMSNorm (w+1) + RoPE (+ optional score scale)
__global__ __launch_bounds__(256)
void rmsrope_kernel(const u16* __restrict__ in, const float* __restrict__ w,
                    u16* __restrict__ out, int n_heads, int tok_stride,
                    int head_stride, float scale) {
  const int warp = (blockIdx.x << 2) + (threadIdx.x >> 6);
  const int lane = threadIdx.x & 63;
  const int h = warp % n_heads;
  const int tok = warp / n_heads;
  const int s = tok & (S_ - 1);
  const int b = tok >> 11;
  const u16* src = in + (size_t)tok * tok_stride + (size_t)h * head_stride;
  float x1 = b2f(src[lane]);
  float x2 = b2f(src[lane + 64]);
  float ss = x1 * x1 + x2 * x2;
#pragma unroll
  for (int off = 1; off < 64; off <<= 1) ss += __shfl_xor(ss, off);
  const float inv = rsqrtf(ss * (1.0f / 128.0f) + 1e-6f) * scale;
  x1 *= inv * (w[lane] + 1.0f);
  x2 *= inv * (w[lane + 64] + 1.0f);
  const float invf = exp2f((float)lane * (-19.931568569324174f / 64.0f));
  const float ang = (float)s * invf;
  float sn, c;
  sincosf(ang, &sn, &c);
  const size_t ob = (((size_t)b * n_heads + h) * S_ + s) * D_;
  out[ob + lane]      = f2b(x1 * c - x2 * sn);
  out[ob + lane + 64] = f2b(x2 * c + x1 * sn);
}

// --------------------------- flash attention: 2-wave split-K per 32-row strip,
// 32x32x16 MFMA. Swapped QK^T (S^T = K·Q^T) puts each q-row in one lane-pair:
// row max/sum = in-lane tree + ONE shfl_xor(32). P->bf16 PV B-fragment built
// in registers via pk2 + 4 word-exchanges (no LDS round-trip in the loop).
// K single-buffered with prefetch-after-use; V issued at step start. Defer-max
// THR=8 skips rescale. XCD-pinned grid decode + heavy-strips-first retained.
// All oacc[] indices compile-time (rule #20) via templated epilogue lambdas.
__global__ __launch_bounds__(128, 2)
void attn_kernel(const u16* __restrict__ Q, const u16* __restrict__ Kr,
                 const u16* __restrict__ Vt, const u16* __restrict__ qraw,
                 u16* __restrict__ Ag) {
  // epilogue-only LDS: per-wave f32 O-exchange [32][68] + m/l dumps. 17.9KB.
  __shared__ __align__(16) float Wscr[2][2176];
  __shared__ float Mdump[2][32], Ldump[2][32];

  const int tid = threadIdx.x;
  const int lane = tid & 63;
  const int wv = tid >> 6;  // K-split half (0 = low tiles, 1 = high tiles)
  const int l31 = lane & 31, hi = lane >> 5;

  // XCD-pinned decode: id%8 = (b,kv) group -> one XCD's L2 holds its K/V/Q.
  const int id = blockIdx.x;
  const int grp = id & 7;
  const int b = grp >> 2, kv = grp & 3;
  const int rest = id >> 3;          // 0..255 within group
  const int hh = rest & 3;           // head within kv group
  const int t = 63 - (rest >> 2);    // heavy strips first
  const int h = (kv << 2) | hh;
  const int bh = (b << 4) | h;
  const int rs = t * 32;  // strip q-row base

  const u16* Qb = Q + ((size_t)bh * S_ + rs) * D_;
  const u16* Kb = Kr + ((size_t)b * KV_ + kv) * S_ * D_;
  const u16* Vb = Vt + ((size_t)b * KV_ + kv) * D_ * S_;

  // Q as B-operand: lane holds Q[q=l31][w*16 + hi*8 .. +8] for w=0..7
  bf16x8 qf[8];
#pragma unroll
  for (int w = 0; w < 8; w++)
    qf[w] = *(const bf16x8*)(Qb + (size_t)l31 * D_ + w * 16 + hi * 8);

  float m_s = -1e30f, l_s = 0.f;
  f32x16 oacc[4];
#pragma unroll
  for (int dt = 0; dt < 4; dt++)
#pragma unroll
    for (int i = 0; i < 16; i++) oacc[dt][i] = 0.f;

  // K-range split: wave0 [0,h0), wave1 [h0, t]; wave1 owns the diagonal.
  const int h0 = (t + 2) >> 1;
  const int klo = wv ? h0 : 0;
  const int khi = wv ? (t + 1) : h0;

  bf16x8 kf[8];  // single buffer, prefetch-after-use (WAR-safe)
  auto loadK = [&](int jt) {
    const u16* kp = Kb + (size_t)(jt * 32 + l31) * D_ + hi * 8;
#pragma unroll
    for (int w = 0; w < 8; w++) kf[w] = *(const bf16x8*)(kp + w * 16);
  };

  auto step = [&](int jt) {
    const int j0 = jt * 32;
    // V A-fragments for this tile (consumed after softmax) — issue first
    bf16x8 vf[8];  // [dt*2+kk]
#pragma unroll
    for (int dt = 0; dt < 4; dt++)
#pragma unroll
      for (int kk = 0; kk < 2; kk++)
        vf[dt * 2 + kk] = *(const bf16x8*)(
            Vb + (size_t)(dt * 32 + l31) * S_ + j0 + kk * 16 + hi * 8);

    // S^T = K·Q^T, two independent 4-deep chains over d
    f32x16 s0, s1;
#pragma unroll
    for (int i = 0; i < 16; i++) { s0[i] = 0.f; s1[i] = 0.f; }
#pragma unroll
    for (int dc = 0; dc < 4; dc++) {
      s0 = __builtin_amdgcn_mfma_f32_32x32x16_bf16(kf[2 * dc], qf[2 * dc], s0,
                                                   0, 0, 0);
      s1 = __builtin_amdgcn_mfma_f32_32x32x16_bf16(kf[2 * dc + 1],
                                                   qf[2 * dc + 1], s1, 0, 0, 0);
    }
    // prefetch next tile's K into the (now-read) buffer
    if (jt + 1 < khi) loadK(jt + 1);
    f32x16 s = s0 + s1;

    if (jt == t) {  // diagonal tile causal mask: k_local > q_local
#pragma unroll
      for (int r = 0; r < 16; r++) {
        const int kl = (r & 3) + 8 * (r >> 2) + 4 * hi;
        if (kl > l31) s[r] = -1e30f;
      }
    }
    // row max: in-lane tree + one cross-half shuffle
    float mx4[4];
#pragma unroll
    for (int g = 0; g < 4; g++)
      mx4[g] = fmaxf(fmaxf(s[4 * g], s[4 * g + 1]),
                     fmaxf(s[4 * g + 2], s[4 * g + 3]));
    float mx = fmaxf(fmaxf(mx4[0], mx4[1]), fmaxf(mx4[2], mx4[3]));
    mx = fmaxf(mx, __shfl_xor(mx, 32));
    // defer-max (THR=8): skip rescale while growth bounded
    const bool defer = __all(mx - m_s <= 8.f);
    const float mn = defer ? m_s : fmaxf(m_s, mx);
    if (!defer) {
      const float alpha = __expf(m_s - mn);
      m_s = mn;
      l_s *= alpha;
#pragma unroll
      for (int dt = 0; dt < 4; dt++)
#pragma unroll
        for (int i = 0; i < 16; i++) oacc[dt][i] *= alpha;
    }
    // exp + row sum
    float rs4[4];
#pragma unroll
    for (int g = 0; g < 4; g++) {
      float e0 = __expf(s[4 * g + 0] - mn);
      float e1 = __expf(s[4 * g + 1] - mn);
      float e2 = __expf(s[4 * g + 2] - mn);
      float e3 = __expf(s[4 * g + 3] - mn);
      s[4 * g + 0] = e0; s[4 * g + 1] = e1;
      s[4 * g + 2] = e2; s[4 * g + 3] = e3;
      rs4[g] = (e0 + e1) + (e2 + e3);
    }
    float rsum = (rs4[0] + rs4[1]) + (rs4[2] + rs4[3]);
    rsum += __shfl_xor(rsum, 32);
    l_s += rsum;
    // pack P to bf16 words and exchange across lane-halves to build B-frags:
    // kk=0 needs k=8*hi..8*hi+7; kk=1 needs k=16+8*hi..+7.
    unsigned a0 = pk2(s[0], s[1]),  b0 = pk2(s[2], s[3]);    // k01/k23 (hi0) | k45/k67 (hi1)
    unsigned c0 = pk2(s[4], s[5]),  d0 = pk2(s[6], s[7]);    // k89/k10,11   | k12,13/k14,15
    unsigned e0 = pk2(s[8], s[9]),  f0 = pk2(s[10], s[11]);  // k16,17/k18,19| k20,21/k22,23
    unsigned g0 = pk2(s[12], s[13]), h0w = pk2(s[14], s[15]); // k24..27     | k28..31
    unsigned r1 = __shfl_xor(hi ? a0 : c0, 32);
    unsigned r2 = __shfl_xor(hi ? b0 : d0, 32);
    unsigned r3 = __shfl_xor(hi ? e0 : g0, 32);
    unsigned r4 = __shfl_xor(hi ? f0 : h0w, 32);
    union U16B { unsigned u[4]; bf16x8 v; };
    U16B p0, p1;
    p0.u[0] = hi ? r1 : a0;  p0.u[1] = hi ? r2 : b0;
    p0.u[2] = hi ? c0 : r1;  p0.u[3] = hi ? d0 : r2;
    p1.u[0] = hi ? r3 : e0;  p1.u[1] = hi ? r4 : f0;
    p1.u[2] = hi ? g0 : r3;  p1.u[3] = hi ? h0w : r4;
    // PV: O^T[d][q] accumulate, 4 independent d-tiles x 2 chained k-halves
#pragma unroll
    for (int dt = 0; dt < 4; dt++) {
      oacc[dt] = __builtin_amdgcn_mfma_f32_32x32x16_bf16(vf[dt * 2], p0.v,
                                                         oacc[dt], 0, 0, 0);
      oacc[dt] = __builtin_amdgcn_mfma_f32_32x32x16_bf16(vf[dt * 2 + 1], p1.v,
                                                         oacc[dt], 0, 0, 0);
    }
  };

  if (klo < khi) {
    loadK(klo);
    for (int jt = klo; jt < khi; jt++) step(jt);
  }

  // ---- cross-wave flash merge. Phase 1: dump COMPLEMENTARY half (dts) + m,l.
  float* myscr = &Wscr[wv][0];
  auto dumpO = [&](auto wvc) {
    constexpr int WV = decltype(wvc)::value;
#pragma unroll
    for (int i = 0; i < 2; i++) {
      constexpr int base = 0;  // (silence unused warnings pattern)
      (void)base;
#pragma unroll
      for (int g = 0; g < 4; g++) {
        f32x4 w;
        w[0] = oacc[(1 - WV) * 2 + i][4 * g + 0];
        w[1] = oacc[(1 - WV) * 2 + i][4 * g + 1];
        w[2] = oacc[(1 - WV) * 2 + i][4 * g + 2];
        w[3] = oacc[(1 - WV) * 2 + i][4 * g + 3];
        *(f32x4*)&myscr[l31 * 68 + i * 32 + 8 * g + 4 * hi] = w;
      }
    }
    if (hi == 0) {
      Mdump[WV][l31] = m_s;
      Ldump[WV][l31] = l_s;
    }
  };
  if (wv == 0) dumpO(ic<0>{}); else dumpO(ic<1>{});
  __syncthreads();
  // Phase 2: finalize OWN half (merge + gate + store).
  auto finO = [&](auto wvc) {
    constexpr int WV = decltype(wvc)::value;
    const float* oscr = &Wscr[1 - WV][0];
    const float mo = Mdump[1 - WV][l31];
    const float lo2 = Ldump[1 - WV][l31];
    const float mm = fmaxf(m_s, mo);
    const float as = __expf(m_s - mm), ao = __expf(mo - mm);
    const float linv = 1.f / (l_s * as + lo2 * ao);
    const size_t tok = (size_t)b * S_ + rs + l31;
    const u16* gp = qraw + tok * 4096 + h * 256 + 128;
    u16* op = Ag + tok * 2048 + h * 128;
#pragma unroll
    for (int i = 0; i < 2; i++) {
#pragma unroll
      for (int g = 0; g < 4; g++) {
        const int dbase = (WV * 2 + i) * 32 + 8 * g + 4 * hi;
        f32x4 oo = *(const f32x4*)&oscr[l31 * 68 + i * 32 + 8 * g + 4 * hi];
        uint2 gv = *(const uint2*)(gp + dbase);
        float g0 = b2f((u16)(gv.x & 0xffff)), g1 = b2f((u16)(gv.x >> 16));
        float g2 = b2f((u16)(gv.y & 0xffff)), g3 = b2f((u16)(gv.y >> 16));
        float o0 = (oacc[WV * 2 + i][4 * g + 0] * as + oo[0] * ao) * linv /
                   (1.f + __expf(-g0));
        float o1 = (oacc[WV * 2 + i][4 * g + 1] * as + oo[1] * ao) * linv /
                   (1.f + __expf(-g1));
        float o2 = (oacc[WV * 2 + i][4 * g + 2] * as + oo[2] * ao) * linv /
                   (1.f + __expf(-g2));
        float o3 = (oacc[WV * 2 + i][4 * g + 3] * as + oo[3] * ao) * linv /
                   (1.f + __expf(-g3));
        *(uint2*)(op + dbase) = make_uint2(pk2(o0, o1), pk2(o2, o3));
      }
    }
  };
  if (wv == 0) finO(ic<0>{}); else finO(ic<1>{});
}

extern "C" void kernel_launch(void* const* d_in, const int* in_sizes, int n_in,
                              void* d_out, int out_size, void* d_ws,
                              size_t ws_size, hipStream_t stream) {
  const float* x  = (const float*)d_in[0];
  const float* Wq = (const float*)d_in[1];
  const float* Wk = (const float*)d_in[2];
  const float* Wv = (const float*)d_in[3];
  const float* Wo = (const float*)d_in[4];
  const float* qn = (const float*)d_in[5];
  const float* kn = (const float*)d_in[6];
  float* out = (float*)d_out;
  char* ws = (char*)d_ws;

  u16* xb    = (u16*)(ws + 0);          // 16.8 MB  x bf16 (4096x2048)
  u16* Wqt   = (u16*)(ws + 16777216);   // 16.8 MB  Wq^T (4096x2048)
  u16* Wkvt  = (u16*)(ws + 33554432);   //  4.2 MB  [Wk^T; Wv^T] (1024x2048)
  u16* Wot   = (u16*)(ws + 37748736);   //  8.4 MB  Wo^T (2048x2048)
  u16* qraw  = (u16*)(ws + 46137344);   // 33.6 MB  q_raw (4096x4096)
  u16* kvraw = (u16*)(ws + 79691776);   //  8.4 MB  [k|v] (4096x1024)
  u16* Vtb   = (u16*)(ws + 88080384);   //  4.2 MB  V^T (B,KV,D,S)
  u16* Kr    = (u16*)(ws + 92274688);   //  4.2 MB  K roped (B,KV,S,D)
  u16* Ag    = (u16*)(ws + 96468992);   // 16.8 MB  gated attn (4096x2048)
  u16* Qr = xb;  // (B,H,S,D) roped+scaled Q (aliases xb, dead after GEMMs)

  cast_f2b_kernel<<<8192, 256, 0, stream>>>(x, xb, 4096 * 2048);
  transpose_w_kernel<<<dim3(128, 64), dim3(32, 8), 0, stream>>>(Wq, Wqt, 2048, 4096);
  transpose_w_kernel<<<dim3(16, 64), dim3(32, 8), 0, stream>>>(Wk, Wkvt, 2048, 512);
  transpose_w_kernel<<<dim3(16, 64), dim3(32, 8), 0, stream>>>(Wv, Wkvt + 512 * 2048,
                                                               2048, 512);
  transpose_w_kernel<<<dim3(64, 64), dim3(32, 8), 0, stream>>>(Wo, Wot, 2048, 2048);

  gemm_nt<u16><<<dim3(32, 32), 256, 0, stream>>>(xb, Wqt, qraw, 4096, 4096, 2048);
  gemm_nt<u16><<<dim3(8, 32), 256, 0, stream>>>(xb, Wkvt, kvraw, 4096, 1024, 2048);

  // softmax scale folded into Q (Q only feeds scores; gate comes from qraw)
  rmsrope_kernel<<<16384, 256, 0, stream>>>(qraw, qn, Qr, 16, 4096, 256,
                                            0.08838834764831845f);
  rmsrope_kernel<<<4096, 256, 0, stream>>>(kvraw, kn, Kr, 4, 1024, 128, 1.0f);
  transpose_v_kernel<<<dim3(64, 4, 8), dim3(32, 8), 0, stream>>>(kvraw + 512, Vtb,
                                                                 1024);

  attn_kernel<<<2048, 128, 0, stream>>>(Qr, Kr, Vtb, qraw, Ag);
  gemm_nt<float><<<dim3(16, 32), 256, 0, stream>>>(Ag, Wot, out, 4096, 2048, 2048);
}

// Round 5
// 432.840 us; speedup vs baseline: 1.1726x; 1.1517x over previous
//
#include <hip/hip_runtime.h>
#include <hip/hip_bf16.h>

typedef unsigned short u16;
typedef __bf16 bf16x8 __attribute__((ext_vector_type(8)));
typedef float f32x4 __attribute__((ext_vector_type(4)));
typedef float f32x16 __attribute__((ext_vector_type(16)));

#define B_   2
#define S_   2048
#define HID_ 2048
#define H_   16
#define KV_  4
#define D_   128

template <int V> struct ic { static constexpr int value = V; };

__device__ __forceinline__ u16 f2b(float f) {
  unsigned u = __float_as_uint(f);
  return (u16)((u + 0x7fffu + ((u >> 16) & 1u)) >> 16);  // RNE
}
__device__ __forceinline__ float b2f(u16 h) {
  return __uint_as_float(((unsigned)h) << 16);
}
__device__ __forceinline__ unsigned pk2(float a, float b) {
  __hip_bfloat162 h = __float22bfloat162_rn(make_float2(a, b));
  unsigned u;
  __builtin_memcpy(&u, &h, 4);
  return u;  // a low 16, b high 16
}
__device__ __forceinline__ void cstore(float* p, float v) { *p = v; }
__device__ __forceinline__ void cstore(u16* p, float v)   { *p = f2b(v); }

// async global->LDS, 16B per lane; LDS dest = wave-uniform base + lane*16
__device__ __forceinline__ void gl_lds16(const u16* g, u16* l) {
  __builtin_amdgcn_global_load_lds(
      (const __attribute__((address_space(1))) unsigned int*)g,
      (__attribute__((address_space(3))) unsigned int*)l, 16, 0, 0);
}

// ---------------------------------------------------------------- cast x -> bf16
__global__ __launch_bounds__(256)
void cast_f2b_kernel(const float* __restrict__ in, u16* __restrict__ out, int n) {
  int i = (blockIdx.x * 256 + threadIdx.x) * 4;
  if (i + 3 < n) {
    float4 v = *(const float4*)(in + i);
    uint2 r = make_uint2(pk2(v.x, v.y), pk2(v.z, v.w));
    *(uint2*)(out + i) = r;
  }
}

// ------------------------------------------- W (R x C) fp32 -> Wt (C x R) bf16
__global__ __launch_bounds__(256)
void transpose_w_kernel(const float* __restrict__ in, u16* __restrict__ out,
                        int R, int Cc) {
  __shared__ u16 t[32][33];
  const int tx = threadIdx.x, ty = threadIdx.y;
  const int c0 = blockIdx.x * 32, r0 = blockIdx.y * 32;
#pragma unroll
  for (int i = 0; i < 4; i++)
    t[ty + i * 8][tx] = f2b(in[(size_t)(r0 + ty + i * 8) * Cc + c0 + tx]);
  __syncthreads();
#pragma unroll
  for (int i = 0; i < 4; i++)
    out[(size_t)(c0 + ty + i * 8) * R + r0 + tx] = t[tx][ty + i * 8];
}

// ------- v slice of kvraw (tok, TS) -> V fragment layout:
// Vf[(b,kv)][jt][f=dt*2+kk][lane=hi*32+d31][e] — lane e-chunk holds
// V[s = jt*32 + kk*16 + hi*8 + e][d = dt*32 + d31]. Every attn V load is then
// a coalesced 1KB wave read.
__global__ __launch_bounds__(256)
void transpose_v_kernel(const u16* __restrict__ in, u16* __restrict__ out,
                        int tokstride) {
  __shared__ u16 t[32][33];
  const int tx = threadIdx.x, ty = threadIdx.y;
  const int jt = blockIdx.x, dt = blockIdx.y;
  const int s0 = jt * 32, d0 = dt * 32;
  const int z = blockIdx.z, b = z >> 2, kv = z & 3;
#pragma unroll
  for (int i = 0; i < 4; i++)
    t[ty + i * 8][tx] =
        in[(size_t)(b * S_ + s0 + ty + i * 8) * tokstride + kv * D_ + d0 + tx];
  __syncthreads();
  const int tid = ty * 32 + tx;
  if (tid < 128) {
    const int kk = tid >> 6, hi2 = (tid >> 5) & 1, d31 = tid & 31;
    u16 vals[8];
#pragma unroll
    for (int e = 0; e < 8; e++) vals[e] = t[kk * 16 + hi2 * 8 + e][d31];
    const size_t off =
        ((((size_t)(b * KV_ + kv) * 64 + jt) * 8 + dt * 2 + kk) * 64 +
         hi2 * 32 + d31) * 8;
    *(uint4*)(out + off) = *(const uint4*)vals;
  }
}

// --------------------------------- NT GEMM: A (M,K) bf16, Bt (N,K) bf16, C (M,N)
// m97 structure: 128x128 tile, BK=32, global_load_lds width=16, unpadded LDS.
template <typename CT>
__global__ __launch_bounds__(256)
void gemm_nt(const u16* __restrict__ A, const u16* __restrict__ Bt,
             CT* __restrict__ C, int Md, int Nd, int Kd) {
  __shared__ u16 As[128 * 32];
  __shared__ u16 Bs[128 * 32];
  const int tid = threadIdx.x;
  const int lane = tid & 63;
  const int wave = tid >> 6;
  const int wm = wave >> 1, wn = wave & 1;
  const int li = lane & 15, quad = lane >> 4;
  const int m0 = blockIdx.y * 128;
  const int n0 = blockIdx.x * 128;

  f32x4 acc[4][4];
#pragma unroll
  for (int i = 0; i < 4; i++)
#pragma unroll
    for (int j = 0; j < 4; j++) acc[i][j] = (f32x4){0.f, 0.f, 0.f, 0.f};

  const int srow = wave * 32 + (lane >> 2);
  const int scol = (lane & 3) * 8;
  const u16* Ag0 = A + (size_t)(m0 + srow) * Kd + scol;
  const u16* Ag1 = Ag0 + (size_t)16 * Kd;
  const u16* Bg0 = Bt + (size_t)(n0 + srow) * Kd + scol;
  const u16* Bg1 = Bg0 + (size_t)16 * Kd;
  u16* Al0 = &As[(wave * 32) * 32];
  u16* Al1 = &As[(wave * 32 + 16) * 32];
  u16* Bl0 = &Bs[(wave * 32) * 32];
  u16* Bl1 = &Bs[(wave * 32 + 16) * 32];

  for (int k0 = 0; k0 < Kd; k0 += 32) {
    __syncthreads();
    gl_lds16(Ag0 + k0, Al0);
    gl_lds16(Ag1 + k0, Al1);
    gl_lds16(Bg0 + k0, Bl0);
    gl_lds16(Bg1 + k0, Bl1);
    __syncthreads();
    bf16x8 af[4], bfr[4];
#pragma unroll
    for (int mt = 0; mt < 4; mt++)
      af[mt] = *(const bf16x8*)&As[(wm * 64 + mt * 16 + li) * 32 + quad * 8];
#pragma unroll
    for (int nt = 0; nt < 4; nt++)
      bfr[nt] = *(const bf16x8*)&Bs[(wn * 64 + nt * 16 + li) * 32 + quad * 8];
#pragma unroll
    for (int mt = 0; mt < 4; mt++)
#pragma unroll
      for (int nt = 0; nt < 4; nt++)
        acc[mt][nt] = __builtin_amdgcn_mfma_f32_16x16x32_bf16(
            af[mt], bfr[nt], acc[mt][nt], 0, 0, 0);
  }
#pragma unroll
  for (int mt = 0; mt < 4; mt++) {
    const int row = m0 + wm * 64 + mt * 16 + quad * 4;
#pragma unroll
    for (int nt = 0; nt < 4; nt++) {
      const int col = n0 + wn * 64 + nt * 16 + li;
#pragma unroll
      for (int r = 0; r < 4; r++)
        cstore(&C[(size_t)(row + r) * Nd + col], acc[mt][nt][r]);
    }
  }
}

// ------------- fused RMSNorm (w+1) + RoPE, storing MFMA-fragment layout:
// out[((b*nh+h)*64 + s>>5)*4096 + (w*64 + hi*32 + (s&31))*8 + e] where
// d = w*16 + hi*8 + e. Lane d and d+64 -> offsets o1 and o1+2048.
__global__ __launch_bounds__(256)
void rmsrope_kernel(const u16* __restrict__ in, const float* __restrict__ w,
                    u16* __restrict__ out, int n_heads, int tok_stride,
                    int head_stride, float scale) {
  const int warp = (blockIdx.x << 2) + (threadIdx.x >> 6);
  const int lane = threadIdx.x & 63;
  const int h = warp % n_heads;
  const int tok = warp / n_heads;
  const int s = tok & (S_ - 1);
  const int b = tok >> 11;
  const u16* src = in + (size_t)tok * tok_stride + (size_t)h * head_stride;
  float x1 = b2f(src[lane]);
  float x2 = b2f(src[lane + 64]);
  float ss = x1 * x1 + x2 * x2;
#pragma unroll
  for (int off = 1; off < 64; off <<= 1) ss += __shfl_xor(ss, off);
  const float inv = rsqrtf(ss * (1.0f / 128.0f) + 1e-6f) * scale;
  x1 *= inv * (w[lane] + 1.0f);
  x2 *= inv * (w[lane + 64] + 1.0f);
  const float invf = exp2f((float)lane * (-19.931568569324174f / 64.0f));
  const float ang = (float)s * invf;
  float sn, c;
  sincosf(ang, &sn, &c);
  const int wq = lane >> 4, hi = (lane >> 3) & 1, e = lane & 7;
  const size_t tb = (((size_t)b * n_heads + h) * 64 + (s >> 5)) * 4096;
  const size_t o1 = tb + (size_t)(wq * 64 + hi * 32 + (s & 31)) * 8 + e;
  out[o1]        = f2b(x1 * c - x2 * sn);
  out[o1 + 2048] = f2b(x2 * c + x1 * sn);
}

// --------------------------- flash attention: 2-wave split-K per 32-row strip,
// 32x32x16 MFMA, swapped QK^T, in-register P exchange, defer-max THR=8,
// XCD-pinned grid decode, heavy-strips-first. Q/K/V are PRE-FRAGMENTED
// ([tile][frag][lane][8]) so every global load in the loop is a fully
// coalesced 1KB wave read (16 cache lines/instr vs 64 for strided rows —
// the R4 bottleneck was vector-memory line-transaction throughput).
// All oacc[] indices compile-time (rule #20) via templated epilogue lambdas.
__global__ __launch_bounds__(128, 2)
void attn_kernel(const u16* __restrict__ Q, const u16* __restrict__ Kr,
                 const u16* __restrict__ Vt, const u16* __restrict__ qraw,
                 u16* __restrict__ Ag) {
  // epilogue-only LDS: per-wave f32 O-exchange [32][68] + m/l dumps. 17.9KB.
  __shared__ __align__(16) float Wscr[2][2176];
  __shared__ float Mdump[2][32], Ldump[2][32];

  const int tid = threadIdx.x;
  const int lane = tid & 63;
  const int wv = tid >> 6;  // K-split half (0 = low tiles, 1 = high tiles)
  const int l31 = lane & 31, hi = lane >> 5;

  // XCD-pinned decode: id%8 = (b,kv) group -> one XCD's L2 holds its K/V/Q.
  const int id = blockIdx.x;
  const int grp = id & 7;
  const int b = grp >> 2, kv = grp & 3;
  const int rest = id >> 3;          // 0..255 within group
  const int hh = rest & 3;           // head within kv group
  const int t = 63 - (rest >> 2);    // heavy strips first
  const int h = (kv << 2) | hh;
  const int bh = (b << 4) | h;
  const int rs = t * 32;  // strip q-row base

  const u16* Qb = Q + ((size_t)bh * 64 + t) * 4096;
  const u16* Kb = Kr + (size_t)(b * KV_ + kv) * 64 * 4096;
  const u16* Vb = Vt + (size_t)(b * KV_ + kv) * 64 * 4096;

  // Q as B-operand: lane holds Q[q=l31][w*16 + hi*8 .. +8] for w=0..7
  bf16x8 qf[8];
#pragma unroll
  for (int w = 0; w < 8; w++)
    qf[w] = *(const bf16x8*)(Qb + w * 512 + lane * 8);

  float m_s = -1e30f, l_s = 0.f;
  f32x16 oacc[4];
#pragma unroll
  for (int dt = 0; dt < 4; dt++)
#pragma unroll
    for (int i = 0; i < 16; i++) oacc[dt][i] = 0.f;

  // K-range split: wave0 [0,h0), wave1 [h0, t]; wave1 owns the diagonal.
  const int h0 = (t + 2) >> 1;
  const int klo = wv ? h0 : 0;
  const int khi = wv ? (t + 1) : h0;

  bf16x8 kf[8];  // single buffer, prefetch-after-use (WAR-safe)
  auto loadK = [&](int jt) {
    const u16* kp = Kb + (size_t)jt * 4096 + lane * 8;
#pragma unroll
    for (int w = 0; w < 8; w++) kf[w] = *(const bf16x8*)(kp + w * 512);
  };

  auto step = [&](int jt) {
    // V A-fragments for this tile (consumed after softmax) — issue first
    const u16* vp = Vb + (size_t)jt * 4096 + lane * 8;
    bf16x8 vf[8];  // [dt*2+kk]
#pragma unroll
    for (int f = 0; f < 8; f++)
      vf[f] = *(const bf16x8*)(vp + f * 512);

    // S^T = K·Q^T, two independent 4-deep chains over d
    f32x16 s0, s1;
#pragma unroll
    for (int i = 0; i < 16; i++) { s0[i] = 0.f; s1[i] = 0.f; }
#pragma unroll
    for (int dc = 0; dc < 4; dc++) {
      s0 = __builtin_amdgcn_mfma_f32_32x32x16_bf16(kf[2 * dc], qf[2 * dc], s0,
                                                   0, 0, 0);
      s1 = __builtin_amdgcn_mfma_f32_32x32x16_bf16(kf[2 * dc + 1],
                                                   qf[2 * dc + 1], s1, 0, 0, 0);
    }
    // prefetch next tile's K into the (now-read) buffer
    if (jt + 1 < khi) loadK(jt + 1);
    f32x16 s = s0 + s1;

    if (jt == t) {  // diagonal tile causal mask: k_local > q_local
#pragma unroll
      for (int r = 0; r < 16; r++) {
        const int kl = (r & 3) + 8 * (r >> 2) + 4 * hi;
        if (kl > l31) s[r] = -1e30f;
      }
    }
    // row max: in-lane tree + one cross-half shuffle
    float mx4[4];
#pragma unroll
    for (int g = 0; g < 4; g++)
      mx4[g] = fmaxf(fmaxf(s[4 * g], s[4 * g + 1]),
                     fmaxf(s[4 * g + 2], s[4 * g + 3]));
    float mx = fmaxf(fmaxf(mx4[0], mx4[1]), fmaxf(mx4[2], mx4[3]));
    mx = fmaxf(mx, __shfl_xor(mx, 32));
    // defer-max (THR=8): skip rescale while growth bounded
    const bool defer = __all(mx - m_s <= 8.f);
    const float mn = defer ? m_s : fmaxf(m_s, mx);
    if (!defer) {
      const float alpha = __expf(m_s - mn);
      m_s = mn;
      l_s *= alpha;
#pragma unroll
      for (int dt = 0; dt < 4; dt++)
#pragma unroll
        for (int i = 0; i < 16; i++) oacc[dt][i] *= alpha;
    }
    // exp + row sum
    float rs4[4];
#pragma unroll
    for (int g = 0; g < 4; g++) {
      float e0 = __expf(s[4 * g + 0] - mn);
      float e1 = __expf(s[4 * g + 1] - mn);
      float e2 = __expf(s[4 * g + 2] - mn);
      float e3 = __expf(s[4 * g + 3] - mn);
      s[4 * g + 0] = e0; s[4 * g + 1] = e1;
      s[4 * g + 2] = e2; s[4 * g + 3] = e3;
      rs4[g] = (e0 + e1) + (e2 + e3);
    }
    float rsum = (rs4[0] + rs4[1]) + (rs4[2] + rs4[3]);
    rsum += __shfl_xor(rsum, 32);
    l_s += rsum;
    // pack P to bf16 words and exchange across lane-halves to build B-frags:
    // kk=0 needs k=8*hi..8*hi+7; kk=1 needs k=16+8*hi..+7.
    unsigned a0 = pk2(s[0], s[1]),  b0 = pk2(s[2], s[3]);
    unsigned c0 = pk2(s[4], s[5]),  d0 = pk2(s[6], s[7]);
    unsigned e0 = pk2(s[8], s[9]),  f0 = pk2(s[10], s[11]);
    unsigned g0 = pk2(s[12], s[13]), h0w = pk2(s[14], s[15]);
    unsigned r1 = __shfl_xor(hi ? a0 : c0, 32);
    unsigned r2 = __shfl_xor(hi ? b0 : d0, 32);
    unsigned r3 = __shfl_xor(hi ? e0 : g0, 32);
    unsigned r4 = __shfl_xor(hi ? f0 : h0w, 32);
    union U16B { unsigned u[4]; bf16x8 v; };
    U16B p0, p1;
    p0.u[0] = hi ? r1 : a0;  p0.u[1] = hi ? r2 : b0;
    p0.u[2] = hi ? c0 : r1;  p0.u[3] = hi ? d0 : r2;
    p1.u[0] = hi ? r3 : e0;  p1.u[1] = hi ? r4 : f0;
    p1.u[2] = hi ? g0 : r3;  p1.u[3] = hi ? h0w : r4;
    // PV: O^T[d][q] accumulate, 4 independent d-tiles x 2 chained k-halves
#pragma unroll
    for (int dt = 0; dt < 4; dt++) {
      oacc[dt] = __builtin_amdgcn_mfma_f32_32x32x16_bf16(vf[dt * 2], p0.v,
                                                         oacc[dt], 0, 0, 0);
      oacc[dt] = __builtin_amdgcn_mfma_f32_32x32x16_bf16(vf[dt * 2 + 1], p1.v,
                                                         oacc[dt], 0, 0, 0);
    }
  };

  if (klo < khi) {
    loadK(klo);
    for (int jt = klo; jt < khi; jt++) step(jt);
  }

  // ---- cross-wave flash merge. Phase 1: dump COMPLEMENTARY half (dts) + m,l.
  float* myscr = &Wscr[wv][0];
  auto dumpO = [&](auto wvc) {
    constexpr int WV = decltype(wvc)::value;
#pragma unroll
    for (int i = 0; i < 2; i++) {
#pragma unroll
      for (int g = 0; g < 4; g++) {
        f32x4 w;
        w[0] = oacc[(1 - WV) * 2 + i][4 * g + 0];
        w[1] = oacc[(1 - WV) * 2 + i][4 * g + 1];
        w[2] = oacc[(1 - WV) * 2 + i][4 * g + 2];
        w[3] = oacc[(1 - WV) * 2 + i][4 * g + 3];
        *(f32x4*)&myscr[l31 * 68 + i * 32 + 8 * g + 4 * hi] = w;
      }
    }
    if (hi == 0) {
      Mdump[WV][l31] = m_s;
      Ldump[WV][l31] = l_s;
    }
  };
  if (wv == 0) dumpO(ic<0>{}); else dumpO(ic<1>{});
  __syncthreads();
  // Phase 2: finalize OWN half (merge + gate + store).
  auto finO = [&](auto wvc) {
    constexpr int WV = decltype(wvc)::value;
    const float* oscr = &Wscr[1 - WV][0];
    const float mo = Mdump[1 - WV][l31];
    const float lo2 = Ldump[1 - WV][l31];
    const float mm = fmaxf(m_s, mo);
    const float as = __expf(m_s - mm), ao = __expf(mo - mm);
    const float linv = 1.f / (l_s * as + lo2 * ao);
    const size_t tok = (size_t)b * S_ + rs + l31;
    const u16* gp = qraw + tok * 4096 + h * 256 + 128;
    u16* op = Ag + tok * 2048 + h * 128;
#pragma unroll
    for (int i = 0; i < 2; i++) {
#pragma unroll
      for (int g = 0; g < 4; g++) {
        const int dbase = (WV * 2 + i) * 32 + 8 * g + 4 * hi;
        f32x4 oo = *(const f32x4*)&oscr[l31 * 68 + i * 32 + 8 * g + 4 * hi];
        uint2 gv = *(const uint2*)(gp + dbase);
        float g0 = b2f((u16)(gv.x & 0xffff)), g1 = b2f((u16)(gv.x >> 16));
        float g2 = b2f((u16)(gv.y & 0xffff)), g3 = b2f((u16)(gv.y >> 16));
        float o0 = (oacc[WV * 2 + i][4 * g + 0] * as + oo[0] * ao) * linv /
                   (1.f + __expf(-g0));
        float o1 = (oacc[WV * 2 + i][4 * g + 1] * as + oo[1] * ao) * linv /
                   (1.f + __expf(-g1));
        float o2 = (oacc[WV * 2 + i][4 * g + 2] * as + oo[2] * ao) * linv /
                   (1.f + __expf(-g2));
        float o3 = (oacc[WV * 2 + i][4 * g + 3] * as + oo[3] * ao) * linv /
                   (1.f + __expf(-g3));
        *(uint2*)(op + dbase) = make_uint2(pk2(o0, o1), pk2(o2, o3));
      }
    }
  };
  if (wv == 0) finO(ic<0>{}); else finO(ic<1>{});
}

extern "C" void kernel_launch(void* const* d_in, const int* in_sizes, int n_in,
                              void* d_out, int out_size, void* d_ws,
                              size_t ws_size, hipStream_t stream) {
  const float* x  = (const float*)d_in[0];
  const float* Wq = (const float*)d_in[1];
  const float* Wk = (const float*)d_in[2];
  const float* Wv = (const float*)d_in[3];
  const float* Wo = (const float*)d_in[4];
  const float* qn = (const float*)d_in[5];
  const float* kn = (const float*)d_in[6];
  float* out = (float*)d_out;
  char* ws = (char*)d_ws;

  u16* xb    = (u16*)(ws + 0);          // 16.8 MB  x bf16 (4096x2048)
  u16* Wqt   = (u16*)(ws + 16777216);   // 16.8 MB  Wq^T (4096x2048)
  u16* Wkvt  = (u16*)(ws + 33554432);   //  4.2 MB  [Wk^T; Wv^T] (1024x2048)
  u16* Wot   = (u16*)(ws + 37748736);   //  8.4 MB  Wo^T (2048x2048)
  u16* qraw  = (u16*)(ws + 46137344);   // 33.6 MB  q_raw (4096x4096)
  u16* kvraw = (u16*)(ws + 79691776);   //  8.4 MB  [k|v] (4096x1024)
  u16* Vtb   = (u16*)(ws + 88080384);   //  4.2 MB  V fragments (B,KV,64,8,64,8)
  u16* Kr    = (u16*)(ws + 92274688);   //  4.2 MB  K roped fragments
  u16* Ag    = (u16*)(ws + 96468992);   // 16.8 MB  gated attn (4096x2048)
  u16* Qr = xb;  // roped+scaled Q fragments (aliases xb, dead after GEMMs)

  cast_f2b_kernel<<<8192, 256, 0, stream>>>(x, xb, 4096 * 2048);
  transpose_w_kernel<<<dim3(128, 64), dim3(32, 8), 0, stream>>>(Wq, Wqt, 2048, 4096);
  transpose_w_kernel<<<dim3(16, 64), dim3(32, 8), 0, stream>>>(Wk, Wkvt, 2048, 512);
  transpose_w_kernel<<<dim3(16, 64), dim3(32, 8), 0, stream>>>(Wv, Wkvt + 512 * 2048,
                                                               2048, 512);
  transpose_w_kernel<<<dim3(64, 64), dim3(32, 8), 0, stream>>>(Wo, Wot, 2048, 2048);

  gemm_nt<u16><<<dim3(32, 32), 256, 0, stream>>>(xb, Wqt, qraw, 4096, 4096, 2048);
  gemm_nt<u16><<<dim3(8, 32), 256, 0, stream>>>(xb, Wkvt, kvraw, 4096, 1024, 2048);

  // softmax scale folded into Q (Q only feeds scores; gate comes from qraw)
  rmsrope_kernel<<<16384, 256, 0, stream>>>(qraw, qn, Qr, 16, 4096, 256,
                                            0.08838834764831845f);
  rmsrope_kernel<<<4096, 256, 0, stream>>>(kvraw, kn, Kr, 4, 1024, 128, 1.0f);
  transpose_v_kernel<<<dim3(64, 4, 8), dim3(32, 8), 0, stream>>>(kvraw + 512, Vtb,
                                                                 1024);

  attn_kernel<<<2048, 128, 0, stream>>>(Qr, Kr, Vtb, qraw, Ag);
  gemm_nt<float><<<dim3(16, 32), 256, 0, stream>>>(Ag, Wot, out, 4096, 2048, 2048);
}